// Round 1
// baseline (2244.833 us; speedup 1.0000x reference)
//
#include <hip/hip_runtime.h>

typedef __attribute__((ext_vector_type(8))) short bfrag;   // 8 bf16 (4 VGPRs)
typedef __attribute__((ext_vector_type(4))) float f32x4;   // MFMA C/D
typedef __attribute__((ext_vector_type(4))) int i32x4;     // 16B moves

#define NT 512      // seq len
#define NB 64       // batch
#define KD 512      // D == H == 512
#define NG 2048     // 4*H gate rows
#define GB 4        // batch blocks (16 batch each)
#define GH 16       // h-slices (32 dims each)

#define YS_SZ (NT * NB * KD)          // 16777216
#define HT_OFF YS_SZ
#define CT_OFF (YS_SZ + NB * KD)

__device__ __forceinline__ unsigned short f2bf(float f) {
  unsigned u = __float_as_uint(f);
  u += 0x7fffu + ((u >> 16) & 1u);
  return (unsigned short)(u >> 16);
}
__device__ __forceinline__ float bf2f(unsigned short h) {
  return __uint_as_float(((unsigned)h) << 16);
}
__device__ __forceinline__ float sigm(float v) { return 1.f / (1.f + __expf(-v)); }
__device__ __forceinline__ float tanh_f(float v) { return 1.f - 2.f / (__expf(2.f * v) + 1.f); }

// ---------------- fp32 -> bf16 convert (vectorized) ----------------
__global__ __launch_bounds__(256) void cvt_bf16(const float* __restrict__ src,
                                                unsigned short* __restrict__ dst, int n8) {
  int i = blockIdx.x * 256 + threadIdx.x;
  if (i >= n8) return;
  const float4 a = *(const float4*)(src + (size_t)i * 8);
  const float4 b = *(const float4*)(src + (size_t)i * 8 + 4);
  i32x4 v;
  v.x = (int)(f2bf(a.x) | ((unsigned)f2bf(a.y) << 16));
  v.y = (int)(f2bf(a.z) | ((unsigned)f2bf(a.w) << 16));
  v.z = (int)(f2bf(b.x) | ((unsigned)f2bf(b.y) << 16));
  v.w = (int)(f2bf(b.z) | ((unsigned)f2bf(b.w) << 16));
  *(i32x4*)(dst + (size_t)i * 8) = v;
}

// ---------------- Phase A: x_proj[t][n][b] = sum_k W_ih[n][k]*x[t][b][k] + b_ih[n] --------
// grid (NG/64, NT), block 256. A=W (M=n), B=x (N=b), K=512. Output stored [t][n][b].
template <int XP32>
__global__ __launch_bounds__(256) void xproj_gemm(const unsigned short* __restrict__ Wb,
                                                  const unsigned short* __restrict__ Xb,
                                                  const float* __restrict__ bias,
                                                  void* __restrict__ XPv) {
  __shared__ unsigned short Wt[64 * 40];  // padded stride 40 (80B, conflict-light)
  __shared__ unsigned short Xt[64 * 40];
  const int tid = threadIdx.x;
  const int lane = tid & 63, wid = tid >> 6;
  const int g = lane >> 4, cc = lane & 15;
  const int n0 = blockIdx.x * 64;
  const int t = blockIdx.y;
  const size_t m0 = (size_t)t * 64;
  const int srow = tid >> 2, schunk = (tid & 3) * 8;

  f32x4 acc[4] = {};
  for (int kb = 0; kb < KD; kb += 32) {
    __syncthreads();
    *(i32x4*)&Wt[srow * 40 + schunk] = *(const i32x4*)(Wb + (size_t)(n0 + srow) * KD + kb + schunk);
    *(i32x4*)&Xt[srow * 40 + schunk] = *(const i32x4*)(Xb + (m0 + srow) * KD + kb + schunk);
    __syncthreads();
    bfrag af = *(const bfrag*)&Wt[(wid * 16 + cc) * 40 + g * 8];
#pragma unroll
    for (int mt = 0; mt < 4; ++mt) {
      bfrag bf = *(const bfrag*)&Xt[(mt * 16 + cc) * 40 + g * 8];
      acc[mt] = __builtin_amdgcn_mfma_f32_16x16x32_bf16(af, bf, acc[mt], 0, 0, 0);
    }
  }
  const int nl = wid * 16 + g * 4;
  float bi[4];
#pragma unroll
  for (int r = 0; r < 4; ++r) bi[r] = bias[n0 + nl + r];
#pragma unroll
  for (int mt = 0; mt < 4; ++mt) {
#pragma unroll
    for (int r = 0; r < 4; ++r) {
      float v = acc[mt][r] + bi[r];
      size_t idx = ((size_t)t * NG + n0 + nl + r) * 64 + mt * 16 + cc;
      if (XP32) ((float*)XPv)[idx] = v;
      else ((unsigned short*)XPv)[idx] = f2bf(v);
    }
  }
}

// ---------------- Phase B: persistent recurrence ----------------
// grid = 64: blk = bid>>4 (batch block of 16), slice = bid&15 (32 h-dims).
// W_hh slice lives in REGISTERS for all 512 steps; c in registers; h exchanged
// via global hbuf + per-batch-block atomic barrier (16 WGs fan-in).
template <int XP32>
__global__ __launch_bounds__(256, 1) void lstm_rec(const unsigned short* __restrict__ Whh,
                                                   const void* __restrict__ XPv,
                                                   const float* __restrict__ bhh,
                                                   const float* __restrict__ h0,
                                                   const float* __restrict__ c0,
                                                   unsigned short* __restrict__ hbuf,
                                                   unsigned int* __restrict__ bar,
                                                   float* __restrict__ out) {
  __shared__ unsigned short hl[16 * 512];  // h block, XOR-swizzled rows (16KB)
  __shared__ float hf[16 * 33];            // h_new transpose tile (padded)

  const int tid = threadIdx.x;
  const int lane = tid & 63, wid = tid >> 6;
  const int g = lane >> 4, cc = lane & 15;
  const int blk = blockIdx.x >> 4, slice = blockIdx.x & 15;
  const int b0 = blk * 16, d0 = slice * 32;
  unsigned int* cnt = bar + blk * 64;  // 256B apart

  // ---- write our slice of h0 (bf16) into hbuf parity 0
  for (int v = tid; v < 512; v += 256) {
    int br = v >> 5, dd = v & 31;
    hbuf[(b0 + br) * KD + d0 + dd] = f2bf(h0[(b0 + br) * KD + d0 + dd]);
  }
  __syncthreads();
  if (tid == 0) __hip_atomic_fetch_add(cnt, 1u, __ATOMIC_RELEASE, __HIP_MEMORY_SCOPE_AGENT);

  // ---- preload W_hh slice into registers: 2 tiles x 16 k-steps of bf16x8
  // WG-row r in [0,128): dim_local = r>>2, gate = r&3  (n = gate*512 + d0 + dim_local)
  bfrag w[2][16];
#pragma unroll
  for (int j = 0; j < 2; ++j) {
    const int tt = wid * 2 + j;
    const int r = tt * 16 + cc;  // A-operand row = lane&15
    const size_t n = (size_t)(r & 3) * KD + d0 + (r >> 2);
#pragma unroll
    for (int ks = 0; ks < 16; ++ks)
      w[j][ks] = *(const bfrag*)(Whh + n * KD + ks * 32 + g * 8);
  }
  // bias + c0 (thread-local: gate=reg, dim = d0 + tt*4 + g, batch = b0 + cc)
  float bh[2][4], creg[2];
#pragma unroll
  for (int j = 0; j < 2; ++j) {
    const int d = d0 + (wid * 2 + j) * 4 + g;
#pragma unroll
    for (int r = 0; r < 4; ++r) bh[j][r] = bhh[r * KD + d];
    creg[j] = c0[(b0 + cc) * KD + d];
  }

  const int hrow = tid >> 4, hc = tid & 15;

  for (int t = 0; t < NT; ++t) {
    // prefetch x_proj (independent of h; hides under the spin)
    float xp[2][4];
#pragma unroll
    for (int j = 0; j < 2; ++j) {
      const int d = d0 + (wid * 2 + j) * 4 + g;
#pragma unroll
      for (int r = 0; r < 4; ++r) {
        size_t idx = ((size_t)t * NG + r * KD + d) * 64 + b0 + cc;
        xp[j][r] = XP32 ? ((const float*)XPv)[idx] : bf2f(((const unsigned short*)XPv)[idx]);
      }
    }
    // wait for all 16 WGs of this batch block to have published h_t
    if (tid == 0) {
      while (__hip_atomic_load(cnt, __ATOMIC_ACQUIRE, __HIP_MEMORY_SCOPE_AGENT) <
             16u * (unsigned)(t + 1))
        __builtin_amdgcn_s_sleep(2);
    }
    __syncthreads();
    // stage h block (16 x 512 bf16) into swizzled LDS
    {
      const unsigned short* hsrc = hbuf + (size_t)(t & 1) * NB * KD + (size_t)(b0 + hrow) * KD;
#pragma unroll
      for (int j2 = 0; j2 < 4; ++j2) {
        const int off = hc * 16 + j2 * 256;
        i32x4 v = *(const i32x4*)((const char*)hsrc + off);
        *(i32x4*)((char*)hl + hrow * 1024 + (off ^ ((hrow & 7) << 4))) = v;
      }
    }
    __syncthreads();
    // gates = W_slice @ h^T  (D[row=n-local][col=batch])
    f32x4 acc0 = {0.f, 0.f, 0.f, 0.f}, acc1 = {0.f, 0.f, 0.f, 0.f};
#pragma unroll
    for (int ks = 0; ks < 16; ++ks) {
      const int off = ks * 64 + g * 16;
      bfrag hb = *(const bfrag*)((const char*)hl + cc * 1024 + (off ^ ((cc & 7) << 4)));
      acc0 = __builtin_amdgcn_mfma_f32_16x16x32_bf16(w[0][ks], hb, acc0, 0, 0, 0);
      acc1 = __builtin_amdgcn_mfma_f32_16x16x32_bf16(w[1][ks], hb, acc1, 0, 0, 0);
    }
    // pointwise (i,f,g,o all thread-local), scatter h_new into LDS transpose tile
#pragma unroll
    for (int j = 0; j < 2; ++j) {
      const f32x4 a = j ? acc1 : acc0;
      const int tt = wid * 2 + j;
      const int dl = tt * 4 + g;
      float gi = a[0] + xp[j][0] + bh[j][0];
      float gf = a[1] + xp[j][1] + bh[j][1];
      float gg = a[2] + xp[j][2] + bh[j][2];
      float go = a[3] + xp[j][3] + bh[j][3];
      float cn = sigm(gf) * creg[j] + sigm(gi) * tanh_f(gg);
      float hn = sigm(go) * tanh_f(cn);
      creg[j] = cn;
      hf[cc * 33 + dl] = hn;
      if (t == NT - 1) out[CT_OFF + (size_t)(b0 + cc) * KD + d0 + dl] = cn;
    }
    __syncthreads();
    // coalesced publish: hbuf (bf16) + ys[t] (fp32) [+ hT at the end]
    if (tid < 128) {
      const int b = tid >> 3, dg = (tid & 7) * 4;
      float4 hv;
      hv.x = hf[b * 33 + dg];
      hv.y = hf[b * 33 + dg + 1];
      hv.z = hf[b * 33 + dg + 2];
      hv.w = hf[b * 33 + dg + 3];
      unsigned long long pk = (unsigned long long)f2bf(hv.x) |
                              ((unsigned long long)f2bf(hv.y) << 16) |
                              ((unsigned long long)f2bf(hv.z) << 32) |
                              ((unsigned long long)f2bf(hv.w) << 48);
      *(unsigned long long*)(hbuf + (size_t)((t + 1) & 1) * NB * KD + (size_t)(b0 + b) * KD + d0 + dg) = pk;
      *(float4*)(out + (size_t)t * NB * KD + (size_t)(b0 + b) * KD + d0 + dg) = hv;
      if (t == NT - 1)
        *(float4*)(out + HT_OFF + (size_t)(b0 + b) * KD + d0 + dg) = hv;
    }
    __syncthreads();  // drains vmcnt for all waves -> stores visible before release
    if (tid == 0) __hip_atomic_fetch_add(cnt, 1u, __ATOMIC_RELEASE, __HIP_MEMORY_SCOPE_AGENT);
  }
}

extern "C" void kernel_launch(void* const* d_in, const int* in_sizes, int n_in,
                              void* d_out, int out_size, void* d_ws, size_t ws_size,
                              hipStream_t stream) {
  const float* x = (const float*)d_in[0];
  const float* h0 = (const float*)d_in[1];
  const float* c0 = (const float*)d_in[2];
  const float* Wih = (const float*)d_in[3];
  const float* Whh = (const float*)d_in[4];
  const float* bih = (const float*)d_in[5];
  const float* bhh = (const float*)d_in[6];
  float* out = (float*)d_out;
  char* ws = (char*)d_ws;

  // ws layout
  unsigned int* bar = (unsigned int*)ws;                                   // 4KB
  unsigned short* hbuf = (unsigned short*)(ws + 4096);                     // 128KB
  unsigned short* WhhB = (unsigned short*)(ws + 4096 + 131072);            // 2MB
  unsigned short* WihB = (unsigned short*)(ws + 4096 + 131072 + 2097152);  // 2MB
  unsigned short* XB = (unsigned short*)(ws + 4096 + 131072 + 2 * 2097152);  // 32MB
  const size_t xp_off = 4096 + 131072 + 2ull * 2097152 + 33554432;
  void* XP = (void*)(ws + xp_off);
  const bool xp32 = ws_size >= xp_off + (size_t)NT * NG * 64 * 4;

  hipMemsetAsync(ws, 0, 4096, stream);  // barrier counters

  const int nx8 = NT * NB * KD / 8;    // 2097152
  const int nw8 = NG * KD / 8;         // 131072
  cvt_bf16<<<dim3(nx8 / 256), 256, 0, stream>>>(x, XB, nx8);
  cvt_bf16<<<dim3(nw8 / 256), 256, 0, stream>>>(Wih, WihB, nw8);
  cvt_bf16<<<dim3(nw8 / 256), 256, 0, stream>>>(Whh, WhhB, nw8);

  if (xp32) {
    xproj_gemm<1><<<dim3(NG / 64, NT), 256, 0, stream>>>(WihB, XB, bih, XP);
    lstm_rec<1><<<dim3(GB * GH), 256, 0, stream>>>(WhhB, XP, bhh, h0, c0, hbuf, bar, out);
  } else {
    xproj_gemm<0><<<dim3(NG / 64, NT), 256, 0, stream>>>(WihB, XB, bih, XP);
    lstm_rec<0><<<dim3(GB * GH), 256, 0, stream>>>(WhhB, XP, bhh, h0, c0, hbuf, bar, out);
  }
}

// Round 2
// 1637.965 us; speedup vs baseline: 1.3705x; 1.3705x over previous
//
#include <hip/hip_runtime.h>

typedef __attribute__((ext_vector_type(8))) short bfrag;   // 8 bf16 (4 VGPRs)
typedef __attribute__((ext_vector_type(4))) float f32x4;   // MFMA C/D
typedef __attribute__((ext_vector_type(4))) int i32x4;     // 16B moves

#define NT 512      // seq len
#define NB 64       // batch
#define KD 512      // D == H == 512
#define NG 2048     // 4*H gate rows
#define GB 4        // batch blocks (16 batch each)
#define GH 16       // h-slices (32 dims each)

#define YS_SZ (NT * NB * KD)          // 16777216
#define HT_OFF YS_SZ
#define CT_OFF (YS_SZ + NB * KD)

__device__ __forceinline__ unsigned short f2bf(float f) {
  unsigned u = __float_as_uint(f);
  u += 0x7fffu + ((u >> 16) & 1u);
  return (unsigned short)(u >> 16);
}
__device__ __forceinline__ float bf2f(unsigned short h) {
  return __uint_as_float(((unsigned)h) << 16);
}
__device__ __forceinline__ float sigm(float v) { return 1.f / (1.f + __expf(-v)); }
__device__ __forceinline__ float tanh_f(float v) { return 1.f - 2.f / (__expf(2.f * v) + 1.f); }

// ---------------- fp32 -> bf16 convert (vectorized) ----------------
__global__ __launch_bounds__(256) void cvt_bf16(const float* __restrict__ src,
                                                unsigned short* __restrict__ dst, int n8) {
  int i = blockIdx.x * 256 + threadIdx.x;
  if (i >= n8) return;
  const float4 a = *(const float4*)(src + (size_t)i * 8);
  const float4 b = *(const float4*)(src + (size_t)i * 8 + 4);
  i32x4 v;
  v.x = (int)(f2bf(a.x) | ((unsigned)f2bf(a.y) << 16));
  v.y = (int)(f2bf(a.z) | ((unsigned)f2bf(a.w) << 16));
  v.z = (int)(f2bf(b.x) | ((unsigned)f2bf(b.y) << 16));
  v.w = (int)(f2bf(b.z) | ((unsigned)f2bf(b.w) << 16));
  *(i32x4*)(dst + (size_t)i * 8) = v;
}

// ---------------- Phase A: x_proj[t][n][b] = sum_k W_ih[n][k]*x[t][b][k] + b_ih[n] --------
template <int XP32>
__global__ __launch_bounds__(256) void xproj_gemm(const unsigned short* __restrict__ Wb,
                                                  const unsigned short* __restrict__ Xb,
                                                  const float* __restrict__ bias,
                                                  void* __restrict__ XPv) {
  __shared__ unsigned short Wt[64 * 40];
  __shared__ unsigned short Xt[64 * 40];
  const int tid = threadIdx.x;
  const int lane = tid & 63, wid = tid >> 6;
  const int g = lane >> 4, cc = lane & 15;
  const int n0 = blockIdx.x * 64;
  const int t = blockIdx.y;
  const size_t m0 = (size_t)t * 64;
  const int srow = tid >> 2, schunk = (tid & 3) * 8;

  f32x4 acc[4] = {};
  for (int kb = 0; kb < KD; kb += 32) {
    __syncthreads();
    *(i32x4*)&Wt[srow * 40 + schunk] = *(const i32x4*)(Wb + (size_t)(n0 + srow) * KD + kb + schunk);
    *(i32x4*)&Xt[srow * 40 + schunk] = *(const i32x4*)(Xb + (m0 + srow) * KD + kb + schunk);
    __syncthreads();
    bfrag af = *(const bfrag*)&Wt[(wid * 16 + cc) * 40 + g * 8];
#pragma unroll
    for (int mt = 0; mt < 4; ++mt) {
      bfrag bf = *(const bfrag*)&Xt[(mt * 16 + cc) * 40 + g * 8];
      acc[mt] = __builtin_amdgcn_mfma_f32_16x16x32_bf16(af, bf, acc[mt], 0, 0, 0);
    }
  }
  const int nl = wid * 16 + g * 4;
  float bi[4];
#pragma unroll
  for (int r = 0; r < 4; ++r) bi[r] = bias[n0 + nl + r];
#pragma unroll
  for (int mt = 0; mt < 4; ++mt) {
#pragma unroll
    for (int r = 0; r < 4; ++r) {
      float v = acc[mt][r] + bi[r];
      size_t idx = ((size_t)t * NG + n0 + nl + r) * 64 + mt * 16 + cc;
      if (XP32) ((float*)XPv)[idx] = v;
      else ((unsigned short*)XPv)[idx] = f2bf(v);
    }
  }
}

// ---------------- Phase B: persistent recurrence ----------------
// grid = 64: blk = bid>>4 (16 batches), slice = bid&15 (32 dims).
// All cross-WG data moves via RELAXED agent-scope atomics (sc1: bypass L1/L2,
// served at the coherence point / Infinity Cache). No acquire/release cache
// maintenance (no buffer_inv / buffer_wbl2) anywhere in the step loop.
// Ordering: writer drains h stores with vmcnt(0)+barrier before the per-slice
// flag store; readers poll flags (relaxed), then barrier, then sc1 h loads.
template <int XP32>
__global__ __launch_bounds__(256, 1) void lstm_rec(const unsigned short* __restrict__ Whh,
                                                   const void* __restrict__ XPv,
                                                   const float* __restrict__ bhh,
                                                   const float* __restrict__ h0,
                                                   const float* __restrict__ c0,
                                                   unsigned short* __restrict__ hbuf,
                                                   unsigned int* __restrict__ bar,
                                                   float* __restrict__ out) {
  __shared__ unsigned short hl[16 * 512];  // h block, XOR-swizzled rows (16KB)
  __shared__ float hf[16 * 33];            // h_new transpose tile (padded)

  const int tid = threadIdx.x;
  const int lane = tid & 63, wid = tid >> 6;
  const int g = lane >> 4, cc = lane & 15;
  const int blk = blockIdx.x >> 4, slice = blockIdx.x & 15;
  const int b0 = blk * 16, d0 = slice * 32;
  unsigned int* flags = bar + blk * 64;  // 16 slice flags, one cacheline; blocks 256B apart
  unsigned long long* hb64 = (unsigned long long*)hbuf;

  // ---- publish our slice of h0 (bf16, sc1 stores) into hbuf parity 0
  if (tid < 128) {
    const int b = tid >> 3, dg = (tid & 7) * 4;
    const float* hsrc = h0 + (size_t)(b0 + b) * KD + d0 + dg;
    unsigned long long pk = (unsigned long long)f2bf(hsrc[0]) |
                            ((unsigned long long)f2bf(hsrc[1]) << 16) |
                            ((unsigned long long)f2bf(hsrc[2]) << 32) |
                            ((unsigned long long)f2bf(hsrc[3]) << 48);
    size_t ui = ((size_t)(b0 + b) * KD + d0 + dg) >> 2;
    __hip_atomic_store(hb64 + ui, pk, __ATOMIC_RELAXED, __HIP_MEMORY_SCOPE_AGENT);
  }
  asm volatile("s_waitcnt vmcnt(0)" ::: "memory");
  __syncthreads();
  if (tid == 0)
    __hip_atomic_store(flags + slice, 1u, __ATOMIC_RELAXED, __HIP_MEMORY_SCOPE_AGENT);

  // ---- preload W_hh slice into registers: 2 tiles x 16 k-steps of bf16x8
  bfrag w[2][16];
#pragma unroll
  for (int j = 0; j < 2; ++j) {
    const int tt = wid * 2 + j;
    const int r = tt * 16 + cc;  // A-operand row = lane&15
    const size_t n = (size_t)(r & 3) * KD + d0 + (r >> 2);
#pragma unroll
    for (int ks = 0; ks < 16; ++ks)
      w[j][ks] = *(const bfrag*)(Whh + n * KD + ks * 32 + g * 8);
  }
  float bh[2][4], creg[2];
#pragma unroll
  for (int j = 0; j < 2; ++j) {
    const int d = d0 + (wid * 2 + j) * 4 + g;
#pragma unroll
    for (int r = 0; r < 4; ++r) bh[j][r] = bhh[r * KD + d];
    creg[j] = c0[(b0 + cc) * KD + d];
  }

  for (int t = 0; t < NT; ++t) {
    // prefetch x_proj (independent of h; in flight during the poll)
    float xp[2][4];
#pragma unroll
    for (int j = 0; j < 2; ++j) {
      const int d = d0 + (wid * 2 + j) * 4 + g;
#pragma unroll
      for (int r = 0; r < 4; ++r) {
        size_t idx = ((size_t)t * NG + r * KD + d) * 64 + b0 + cc;
        xp[j][r] = XP32 ? ((const float*)XPv)[idx] : bf2f(((const unsigned short*)XPv)[idx]);
      }
    }
    // wait for all 16 slices of this batch block to have published h_t
    // (wave 0: 16 lanes poll 16 flag words = one 64B cacheline per iteration)
    if (wid == 0) {
      const unsigned tgt = (unsigned)(t + 1);
      for (;;) {
        unsigned f = tgt;
        if (lane < 16)
          f = __hip_atomic_load(flags + lane, __ATOMIC_RELAXED, __HIP_MEMORY_SCOPE_AGENT);
        if (__all(f >= tgt)) break;
      }
    }
    __syncthreads();
    // stage h block (16 x 512 bf16 = 16KB) into swizzled LDS; 8 b64 sc1 loads
    // issued back-to-back, then LDS writes
    {
      const unsigned long long* hp =
          hb64 + (size_t)(t & 1) * (NB * KD / 4) + (size_t)b0 * (KD / 4);
      unsigned long long hv8[8];
#pragma unroll
      for (int j = 0; j < 8; ++j)
        hv8[j] = __hip_atomic_load(hp + j * 256 + tid, __ATOMIC_RELAXED, __HIP_MEMORY_SCOPE_AGENT);
#pragma unroll
      for (int j = 0; j < 8; ++j) {
        const int row = j * 2 + (tid >> 7);
        const int colb = (tid & 127) * 8;
        *(unsigned long long*)((char*)hl + row * 1024 + (colb ^ ((row & 7) << 4))) = hv8[j];
      }
    }
    __syncthreads();
    // gates = W_slice @ h^T
    f32x4 acc0 = {0.f, 0.f, 0.f, 0.f}, acc1 = {0.f, 0.f, 0.f, 0.f};
#pragma unroll
    for (int ks = 0; ks < 16; ++ks) {
      const int off = ks * 64 + g * 16;
      bfrag hb = *(const bfrag*)((const char*)hl + cc * 1024 + (off ^ ((cc & 7) << 4)));
      acc0 = __builtin_amdgcn_mfma_f32_16x16x32_bf16(w[0][ks], hb, acc0, 0, 0, 0);
      acc1 = __builtin_amdgcn_mfma_f32_16x16x32_bf16(w[1][ks], hb, acc1, 0, 0, 0);
    }
    // pointwise (i,f,g,o thread-local), scatter h_new into LDS transpose tile
#pragma unroll
    for (int j = 0; j < 2; ++j) {
      const f32x4 a = j ? acc1 : acc0;
      const int tt = wid * 2 + j;
      const int dl = tt * 4 + g;
      float gi = a[0] + xp[j][0] + bh[j][0];
      float gf = a[1] + xp[j][1] + bh[j][1];
      float gg = a[2] + xp[j][2] + bh[j][2];
      float go = a[3] + xp[j][3] + bh[j][3];
      float cn = sigm(gf) * creg[j] + sigm(gi) * tanh_f(gg);
      float hn = sigm(go) * tanh_f(cn);
      creg[j] = cn;
      hf[cc * 33 + dl] = hn;
      if (t == NT - 1) out[CT_OFF + (size_t)(b0 + cc) * KD + d0 + dl] = cn;
    }
    __syncthreads();
    // publish h_{t+1}: bf16 sc1 stores FIRST, drain, flag; ys stores AFTER the
    // flag so their ack latency stays off the critical path.
    float4 hv;
    if (tid < 128) {
      const int b = tid >> 3, dg = (tid & 7) * 4;
      hv.x = hf[b * 33 + dg];
      hv.y = hf[b * 33 + dg + 1];
      hv.z = hf[b * 33 + dg + 2];
      hv.w = hf[b * 33 + dg + 3];
      unsigned long long pk = (unsigned long long)f2bf(hv.x) |
                              ((unsigned long long)f2bf(hv.y) << 16) |
                              ((unsigned long long)f2bf(hv.z) << 32) |
                              ((unsigned long long)f2bf(hv.w) << 48);
      size_t ui = ((size_t)((t + 1) & 1) * NB * KD + (size_t)(b0 + b) * KD + d0 + dg) >> 2;
      __hip_atomic_store(hb64 + ui, pk, __ATOMIC_RELAXED, __HIP_MEMORY_SCOPE_AGENT);
    }
    asm volatile("s_waitcnt vmcnt(0)" ::: "memory");
    __syncthreads();  // all publishing waves drained before the flag
    if (tid == 0)
      __hip_atomic_store(flags + slice, (unsigned)(t + 2), __ATOMIC_RELAXED,
                         __HIP_MEMORY_SCOPE_AGENT);
    if (tid < 128) {
      const int b = tid >> 3, dg = (tid & 7) * 4;
      *(float4*)(out + (size_t)t * NB * KD + (size_t)(b0 + b) * KD + d0 + dg) = hv;
      if (t == NT - 1)
        *(float4*)(out + HT_OFF + (size_t)(b0 + b) * KD + d0 + dg) = hv;
    }
  }
}

extern "C" void kernel_launch(void* const* d_in, const int* in_sizes, int n_in,
                              void* d_out, int out_size, void* d_ws, size_t ws_size,
                              hipStream_t stream) {
  const float* x = (const float*)d_in[0];
  const float* h0 = (const float*)d_in[1];
  const float* c0 = (const float*)d_in[2];
  const float* Wih = (const float*)d_in[3];
  const float* Whh = (const float*)d_in[4];
  const float* bih = (const float*)d_in[5];
  const float* bhh = (const float*)d_in[6];
  float* out = (float*)d_out;
  char* ws = (char*)d_ws;

  unsigned int* bar = (unsigned int*)ws;                                   // 4KB
  unsigned short* hbuf = (unsigned short*)(ws + 4096);                     // 128KB
  unsigned short* WhhB = (unsigned short*)(ws + 4096 + 131072);            // 2MB
  unsigned short* WihB = (unsigned short*)(ws + 4096 + 131072 + 2097152);  // 2MB
  unsigned short* XB = (unsigned short*)(ws + 4096 + 131072 + 2 * 2097152);  // 32MB
  const size_t xp_off = 4096 + 131072 + 2ull * 2097152 + 33554432;
  void* XP = (void*)(ws + xp_off);
  const bool xp32 = ws_size >= xp_off + (size_t)NT * NG * 64 * 4;

  hipMemsetAsync(ws, 0, 4096, stream);  // flag words

  const int nx8 = NT * NB * KD / 8;
  const int nw8 = NG * KD / 8;
  cvt_bf16<<<dim3(nx8 / 256), 256, 0, stream>>>(x, XB, nx8);
  cvt_bf16<<<dim3(nw8 / 256), 256, 0, stream>>>(Wih, WihB, nw8);
  cvt_bf16<<<dim3(nw8 / 256), 256, 0, stream>>>(Whh, WhhB, nw8);

  if (xp32) {
    xproj_gemm<1><<<dim3(NG / 64, NT), 256, 0, stream>>>(WihB, XB, bih, XP);
    lstm_rec<1><<<dim3(GB * GH), 256, 0, stream>>>(WhhB, XP, bhh, h0, c0, hbuf, bar, out);
  } else {
    xproj_gemm<0><<<dim3(NG / 64, NT), 256, 0, stream>>>(WihB, XB, bih, XP);
    lstm_rec<0><<<dim3(GB * GH), 256, 0, stream>>>(WhhB, XP, bhh, h0, c0, hbuf, bar, out);
  }
}